// Round 6
// baseline (167.005 us; speedup 1.0000x reference)
//
#include <hip/hip_runtime.h>

// StableZeroDiv: out = x * (y != 0 ? 1/y : 0), elementwise fp32.
// 67,108,864 fp32 elems/tensor; 768 MB logical traffic -> HBM-bound.
// R5: same as R4 but with a native clang vector type so
// __builtin_nontemporal_store compiles (HIP float4 is a class, rejected).

typedef float f32x4 __attribute__((ext_vector_type(4)));

#define UNROLL 4

__global__ void __launch_bounds__(256)
StableZeroDiv_16561393894029_kernel(const f32x4* __restrict__ x4,
                                    const f32x4* __restrict__ y4,
                                    f32x4* __restrict__ o4,
                                    int n4_main) {
    // n4_main is a multiple of UNROLL*T (launcher guarantees), so
    // base + k*T is always in bounds inside the loop.
    const int T = gridDim.x * blockDim.x;
    const int i0 = blockIdx.x * blockDim.x + threadIdx.x;
    for (int base = i0; base < n4_main; base += UNROLL * T) {
        f32x4 xv[UNROLL], yv[UNROLL];
        // Issue all 8 loads before any use -> 8 outstanding vmem ops.
#pragma unroll
        for (int k = 0; k < UNROLL; ++k) {
            xv[k] = x4[base + k * T];
            yv[k] = y4[base + k * T];
        }
#pragma unroll
        for (int k = 0; k < UNROLL; ++k) {
            f32x4 ov;
#pragma unroll
            for (int c = 0; c < 4; ++c) {
                ov[c] = (yv[k][c] != 0.0f) ? xv[k][c] * (1.0f / yv[k][c])
                                           : 0.0f;
            }
            // Write-once stream: bypass cache allocation (nt store).
            __builtin_nontemporal_store(ov, &o4[base + k * T]);
        }
    }
}

// Simple grid-stride float4 kernel for the remainder [n4_main, n4).
__global__ void __launch_bounds__(256)
StableZeroDiv_16561393894029_rem(const f32x4* __restrict__ x4,
                                 const f32x4* __restrict__ y4,
                                 f32x4* __restrict__ o4,
                                 int start4, int n4) {
    const int stride = gridDim.x * blockDim.x;
    for (int i = start4 + blockIdx.x * blockDim.x + threadIdx.x; i < n4;
         i += stride) {
        f32x4 xv = x4[i];
        f32x4 yv = y4[i];
        f32x4 ov;
#pragma unroll
        for (int c = 0; c < 4; ++c) {
            ov[c] = (yv[c] != 0.0f) ? xv[c] * (1.0f / yv[c]) : 0.0f;
        }
        __builtin_nontemporal_store(ov, &o4[i]);
    }
}

// Scalar tail for n % 4 != 0 (not hit at the bench shape).
__global__ void __launch_bounds__(64)
StableZeroDiv_16561393894029_tail(const float* __restrict__ x,
                                  const float* __restrict__ y,
                                  float* __restrict__ o,
                                  int start, int n) {
    int i = start + blockIdx.x * blockDim.x + threadIdx.x;
    if (i < n) {
        float yv = y[i];
        o[i] = (yv != 0.0f) ? x[i] * (1.0f / yv) : 0.0f;
    }
}

extern "C" void kernel_launch(void* const* d_in, const int* in_sizes, int n_in,
                              void* d_out, int out_size, void* d_ws, size_t ws_size,
                              hipStream_t stream) {
    const float* x = (const float*)d_in[0];
    const float* y = (const float*)d_in[1];
    float* out = (float*)d_out;
    const int n = in_sizes[0];          // 67,108,864
    const int n4 = n / 4;               // 16,777,216 float4 elements

    const int block = 256;
    const int grid = 2048;              // 256 CUs x 8 blocks/CU
    const long T = (long)grid * block;  // 524,288 threads
    const long chunk = (long)UNROLL * T;             // 2,097,152
    const int n4_main = (int)((n4 / chunk) * chunk); // exact at bench shape

    if (n4_main > 0) {
        StableZeroDiv_16561393894029_kernel<<<grid, block, 0, stream>>>(
            (const f32x4*)x, (const f32x4*)y, (f32x4*)out, n4_main);
    }
    if (n4 > n4_main) {
        StableZeroDiv_16561393894029_rem<<<grid, block, 0, stream>>>(
            (const f32x4*)x, (const f32x4*)y, (f32x4*)out, n4_main, n4);
    }
    const int tail_start = n4 * 4;
    if (n > tail_start) {
        StableZeroDiv_16561393894029_tail<<<1, 64, 0, stream>>>(
            x, y, out, tail_start, n);
    }
}

// Round 7
// 157.627 us; speedup vs baseline: 1.0595x; 1.0595x over previous
//
#include <hip/hip_runtime.h>

// StableZeroDiv: out = x * (y != 0 ? 1/y : 0), elementwise fp32.
// 67,108,864 fp32 elems/tensor; 768 MB logical traffic -> HBM-bound.
// R6: revert R5's NT-store + strided-unroll regression (FETCH unchanged,
// occupancy dropped, DRAM stream locality worsened). Back to the R3
// grid-stride float4 structure, but replace the ~10-op IEEE divide
// micro-sequence with single-instruction v_rcp_f32: the VALU dependency
// chain between load-return and next load-issue throttles per-wave
// memory request rate. Accuracy: 1-ulp rcp -> abs err ~1e2 at this data
// distribution, threshold is 4.98e5.

__global__ void __launch_bounds__(256)
StableZeroDiv_16561393894029_kernel(const float4* __restrict__ x4,
                                    const float4* __restrict__ y4,
                                    float4* __restrict__ o4,
                                    int n4) {
    const int stride = gridDim.x * blockDim.x;
    for (int i = blockIdx.x * blockDim.x + threadIdx.x; i < n4; i += stride) {
        float4 xv = x4[i];
        float4 yv = y4[i];
        float4 ov;
        // v_rcp_f32 (approx, 1 ulp); y==0 -> rcp=inf, masked off by select.
        ov.x = (yv.x != 0.0f) ? xv.x * __builtin_amdgcn_rcpf(yv.x) : 0.0f;
        ov.y = (yv.y != 0.0f) ? xv.y * __builtin_amdgcn_rcpf(yv.y) : 0.0f;
        ov.z = (yv.z != 0.0f) ? xv.z * __builtin_amdgcn_rcpf(yv.z) : 0.0f;
        ov.w = (yv.w != 0.0f) ? xv.w * __builtin_amdgcn_rcpf(yv.w) : 0.0f;
        o4[i] = ov;
    }
}

// Scalar tail for n % 4 != 0 (not hit at the bench shape).
__global__ void __launch_bounds__(64)
StableZeroDiv_16561393894029_tail(const float* __restrict__ x,
                                  const float* __restrict__ y,
                                  float* __restrict__ o,
                                  int start, int n) {
    int i = start + blockIdx.x * blockDim.x + threadIdx.x;
    if (i < n) {
        float yv = y[i];
        o[i] = (yv != 0.0f) ? x[i] * __builtin_amdgcn_rcpf(yv) : 0.0f;
    }
}

extern "C" void kernel_launch(void* const* d_in, const int* in_sizes, int n_in,
                              void* d_out, int out_size, void* d_ws, size_t ws_size,
                              hipStream_t stream) {
    const float* x = (const float*)d_in[0];
    const float* y = (const float*)d_in[1];
    float* out = (float*)d_out;
    const int n = in_sizes[0];          // 67,108,864
    const int n4 = n / 4;               // 16,777,216 float4 elements

    // Grid: 256 CUs x 8 blocks/CU = 2048 blocks; grid-stride the rest.
    const int block = 256;
    int grid = (n4 + block - 1) / block;
    if (grid > 2048) grid = 2048;
    if (grid < 1) grid = 1;

    StableZeroDiv_16561393894029_kernel<<<grid, block, 0, stream>>>(
        (const float4*)x, (const float4*)y, (float4*)out, n4);

    const int tail_start = n4 * 4;
    if (n > tail_start) {
        StableZeroDiv_16561393894029_tail<<<1, 64, 0, stream>>>(
            x, y, out, tail_start, n);
    }
}

// Round 8
// 145.563 us; speedup vs baseline: 1.1473x; 1.0829x over previous
//
#include <hip/hip_runtime.h>

// StableZeroDiv: out = x * (y != 0 ? 1/y : 0), elementwise fp32.
// 67,108,864 fp32 elems/tensor; 768 MB logical traffic -> HBM-bound.
// R7: isolate the MLP lever that R5 confounded. Flat launch (no
// grid-stride loop), each thread handles 4 float4s at block-contiguous
// addresses (base + tid + k*256): 8 loads issued back-to-back per thread
// before any use, block touches one contiguous 16 KB window per buffer.
// Plain stores (NT reverted: FETCH unchanged, write path slower).
// rcp kept from R6 (VALUBusy 14.5->5.2%, absmax 0.25 vs 4.98e5 threshold).

#define UNROLL 4

__global__ void __launch_bounds__(256)
StableZeroDiv_16561393894029_kernel(const float4* __restrict__ x4,
                                    const float4* __restrict__ y4,
                                    float4* __restrict__ o4) {
    // Each block: contiguous chunk of UNROLL*256 float4 (16 KB / buffer).
    const int base = blockIdx.x * (UNROLL * 256) + threadIdx.x;
    float4 xv[UNROLL], yv[UNROLL];
    // 8 independent loads in flight before any vmcnt wait.
#pragma unroll
    for (int k = 0; k < UNROLL; ++k) {
        xv[k] = x4[base + k * 256];
        yv[k] = y4[base + k * 256];
    }
#pragma unroll
    for (int k = 0; k < UNROLL; ++k) {
        float4 ov;
        ov.x = (yv[k].x != 0.0f) ? xv[k].x * __builtin_amdgcn_rcpf(yv[k].x) : 0.0f;
        ov.y = (yv[k].y != 0.0f) ? xv[k].y * __builtin_amdgcn_rcpf(yv[k].y) : 0.0f;
        ov.z = (yv[k].z != 0.0f) ? xv[k].z * __builtin_amdgcn_rcpf(yv[k].z) : 0.0f;
        ov.w = (yv[k].w != 0.0f) ? xv[k].w * __builtin_amdgcn_rcpf(yv[k].w) : 0.0f;
        o4[base + k * 256] = ov;
    }
}

// Grid-stride float4 kernel for any remainder [start4, n4).
__global__ void __launch_bounds__(256)
StableZeroDiv_16561393894029_rem(const float4* __restrict__ x4,
                                 const float4* __restrict__ y4,
                                 float4* __restrict__ o4,
                                 int start4, int n4) {
    const int stride = gridDim.x * blockDim.x;
    for (int i = start4 + blockIdx.x * blockDim.x + threadIdx.x; i < n4;
         i += stride) {
        float4 xv = x4[i];
        float4 yv = y4[i];
        float4 ov;
        ov.x = (yv.x != 0.0f) ? xv.x * __builtin_amdgcn_rcpf(yv.x) : 0.0f;
        ov.y = (yv.y != 0.0f) ? xv.y * __builtin_amdgcn_rcpf(yv.y) : 0.0f;
        ov.z = (yv.z != 0.0f) ? xv.z * __builtin_amdgcn_rcpf(yv.z) : 0.0f;
        ov.w = (yv.w != 0.0f) ? xv.w * __builtin_amdgcn_rcpf(yv.w) : 0.0f;
        o4[i] = ov;
    }
}

// Scalar tail for n % 4 != 0 (not hit at the bench shape).
__global__ void __launch_bounds__(64)
StableZeroDiv_16561393894029_tail(const float* __restrict__ x,
                                  const float* __restrict__ y,
                                  float* __restrict__ o,
                                  int start, int n) {
    int i = start + blockIdx.x * blockDim.x + threadIdx.x;
    if (i < n) {
        float yv = y[i];
        o[i] = (yv != 0.0f) ? x[i] * __builtin_amdgcn_rcpf(yv) : 0.0f;
    }
}

extern "C" void kernel_launch(void* const* d_in, const int* in_sizes, int n_in,
                              void* d_out, int out_size, void* d_ws, size_t ws_size,
                              hipStream_t stream) {
    const float* x = (const float*)d_in[0];
    const float* y = (const float*)d_in[1];
    float* out = (float*)d_out;
    const int n = in_sizes[0];          // 67,108,864
    const int n4 = n / 4;               // 16,777,216 float4 elements

    const int chunk = UNROLL * 256;     // float4 per block (1024)
    const int nblocks = n4 / chunk;     // 16384 exactly at bench shape
    const int covered = nblocks * chunk;

    if (nblocks > 0) {
        StableZeroDiv_16561393894029_kernel<<<nblocks, 256, 0, stream>>>(
            (const float4*)x, (const float4*)y, (float4*)out);
    }
    if (n4 > covered) {
        StableZeroDiv_16561393894029_rem<<<64, 256, 0, stream>>>(
            (const float4*)x, (const float4*)y, (float4*)out, covered, n4);
    }
    const int tail_start = n4 * 4;
    if (n > tail_start) {
        StableZeroDiv_16561393894029_tail<<<1, 64, 0, stream>>>(
            x, y, out, tail_start, n);
    }
}